// Round 8
// baseline (1499.141 us; speedup 1.0000x reference)
//
#include <hip/hip_runtime.h>
#include <hip/hip_bf16.h>

#define N_NODES 100000
#define F_IN    512
#define H1      8
#define C1      8
#define D1      64   // H1*C1
#define C2      16
#define SLOPE   0.2f
#define PSHIFT  8     // 256 dsts per partition
#define PPART   391   // ceil(100000/256)
#define CAPP    5120  // per-partition FIFO capacity (avg 4348, +11 sigma)
#define CHUNK   2048  // edges per part-role block

typedef __bf16 bf16_t;
typedef bf16_t bf16x8 __attribute__((ext_vector_type(8)));
typedef float  f32x4  __attribute__((ext_vector_type(4)));

// ---------------------------------------------------------------------------
// W1 [512][64] fp32 -> W1^T [64][512] bf16
// ---------------------------------------------------------------------------
__global__ __launch_bounds__(256) void wcvt_kernel(
    const float* __restrict__ W, bf16_t* __restrict__ Bt)
{
    int i = blockIdx.x * 256 + threadIdx.x;     // over 64*512
    if (i >= 64 * 512) return;
    int nn = i >> 9, k = i & 511;
    Bt[i] = (bf16_t)W[k * 64 + nn];
}

// ---------------------------------------------------------------------------
// MERGED gemm1 || part (independent data; part hides under gemm1).
//   blockIdx <  Gg : gemm1 body (bf16 MFMA + fused al1), 128 rows/block
//   blockIdx >= Gg : part body (partition edges into 391 dst-range FIFOs)
// ---------------------------------------------------------------------------
union PgSmem {
    struct {
        int hist[PPART], lofs[PPART], gbase[PPART], cursor[PPART];
        int sdata[512];
        int2 fifo[CHUNK];
    } part;
    bf16_t Bsm[8 * 4 * 64 * 8];
};

__global__ __launch_bounds__(512, 4) void pg_kernel(
    const int* __restrict__ ei, int* __restrict__ pcnt, int2* __restrict__ pfifo,
    const float* __restrict__ X, const bf16_t* __restrict__ Bt,
    const float* __restrict__ a1s, const float* __restrict__ a1d,
    bf16_t* __restrict__ HPb, float* __restrict__ als1, float* __restrict__ ald1,
    int E, int total, int Gg, int n)
{
    __shared__ PgSmem sm;
    const int t = threadIdx.x;

    if ((int)blockIdx.x >= Gg) {
        // ---------------- part body ----------------
        const int chunk0 = ((int)blockIdx.x - Gg) * CHUNK;

        for (int i = t; i < PPART; i += 512) sm.part.hist[i] = 0;
        __syncthreads();

        int srcs[4], dsts[4];
        const int e0 = chunk0 + t * 4;
        if (e0 + 4 <= E) {
            int4 s = *(const int4*)(ei + e0);
            int4 d = *(const int4*)(ei + E + e0);
            srcs[0]=s.x; srcs[1]=s.y; srcs[2]=s.z; srcs[3]=s.w;
            dsts[0]=d.x; dsts[1]=d.y; dsts[2]=d.z; dsts[3]=d.w;
        } else {
#pragma unroll
            for (int j = 0; j < 4; ++j) {
                int e = e0 + j;
                if (e < E)          { srcs[j] = ei[e]; dsts[j] = ei[E + e]; }
                else if (e < total) { srcs[j] = dsts[j] = e - E; }
                else                { srcs[j] = -1;    dsts[j] = -1; }
            }
        }
#pragma unroll
        for (int j = 0; j < 4; ++j)
            if (dsts[j] >= 0) atomicAdd(&sm.part.hist[dsts[j] >> PSHIFT], 1);
        __syncthreads();

        int hv = (t < PPART) ? sm.part.hist[t] : 0;
        sm.part.sdata[t] = hv;
        __syncthreads();
        for (int off = 1; off < 512; off <<= 1) {
            int x = (t >= off) ? sm.part.sdata[t - off] : 0;
            __syncthreads();
            sm.part.sdata[t] += x;
            __syncthreads();
        }
        if (t < PPART) {
            int lo = sm.part.sdata[t] - hv;
            sm.part.lofs[t]   = lo;
            sm.part.cursor[t] = lo;
            sm.part.gbase[t]  = hv ? atomicAdd(&pcnt[t], hv) : 0;
        }
        __syncthreads();

#pragma unroll
        for (int j = 0; j < 4; ++j) {
            if (dsts[j] >= 0) {
                int p = dsts[j] >> PSHIFT;
                int slot = atomicAdd(&sm.part.cursor[p], 1);
                sm.part.fifo[slot] = make_int2(srcs[j], dsts[j]);
            }
        }
        __syncthreads();

        const int w = t >> 6, lane = t & 63;
        for (int p = w; p < PPART; p += 8) {
            int len = sm.part.hist[p];
            int lo  = sm.part.lofs[p];
            int gb  = sm.part.gbase[p];
            int2* dstp = pfifo + (size_t)p * CAPP;
            for (int j = lane; j < len; j += 64) {
                int g = gb + j;
                if (g < CAPP) dstp[g] = sm.part.fifo[lo + j];
            }
        }
        return;
    }

    // ---------------- gemm1 body ----------------
    const int rowbase = (int)blockIdx.x * 128;
    const int w = t >> 6;          // wave 0..7 -> rows w*16..w*16+15
    const int lane = t & 63;

    const int rloc = lane & 15;    // A/B row within 16-group
    const int koff = (lane >> 4) * 8;

    int grow = rowbase + w * 16 + rloc;
    int growc = (grow < n) ? grow : (n - 1);   // clamp for safe loads; store guarded
    const float* arow = X + (size_t)growc * F_IN + koff;

    f32x4 acc[4];
#pragma unroll
    for (int nt = 0; nt < 4; ++nt) acc[nt] = (f32x4){0.f, 0.f, 0.f, 0.f};

#pragma unroll
    for (int half = 0; half < 2; ++half) {
        // stage B fragments for K = half*256 .. half*256+255
        for (int i = t; i < 2048; i += 512) {
            int l9 = i & 63;
            int nt = (i >> 6) & 3;
            int ks = i >> 8;                       // 0..7
            int row = nt * 16 + (l9 & 15);
            int col = (half * 8 + ks) * 32 + (l9 >> 4) * 8;
            *(bf16x8*)(sm.Bsm + (size_t)i * 8) =
                *(const bf16x8*)(Bt + (size_t)row * F_IN + col);
        }
        __syncthreads();

#pragma unroll 4
        for (int ks = 0; ks < 8; ++ks) {
            int kg = (half * 8 + ks) * 32;
            float4 xa0 = *(const float4*)(arow + kg);
            float4 xa1 = *(const float4*)(arow + kg + 4);
            bf16x8 af;
            af[0]=(bf16_t)xa0.x; af[1]=(bf16_t)xa0.y; af[2]=(bf16_t)xa0.z; af[3]=(bf16_t)xa0.w;
            af[4]=(bf16_t)xa1.x; af[5]=(bf16_t)xa1.y; af[6]=(bf16_t)xa1.z; af[7]=(bf16_t)xa1.w;
#pragma unroll
            for (int nt = 0; nt < 4; ++nt) {
                bf16x8 b = *(const bf16x8*)(sm.Bsm + ((ks * 4 + nt) * 64 + lane) * 8);
                acc[nt] = __builtin_amdgcn_mfma_f32_16x16x32_bf16(af, b, acc[nt], 0, 0, 0);
            }
        }
        __syncthreads();
    }

    const int colg = lane & 15;
    const int quad = lane >> 4;
    const int b    = colg >> 3;
    float cs[4], cd[4];
#pragma unroll
    for (int nt = 0; nt < 4; ++nt) {
        cs[nt] = a1s[nt * 16 + colg];
        cd[nt] = a1d[nt * 16 + colg];
    }

#pragma unroll
    for (int i = 0; i < 4; ++i) {
        int r = rowbase + w * 16 + quad * 4 + i;
        bool ok = r < n;
        if (ok) {
            bf16_t* hr = HPb + (size_t)r * D1;
            hr[colg]      = (bf16_t)acc[0][i];
            hr[16 + colg] = (bf16_t)acc[1][i];
            hr[32 + colg] = (bf16_t)acc[2][i];
            hr[48 + colg] = (bf16_t)acc[3][i];
        }
#pragma unroll
        for (int nt = 0; nt < 4; ++nt) {
            float ps = acc[nt][i] * cs[nt];
            float pd = acc[nt][i] * cd[nt];
            ps += __shfl_xor(ps, 1, 64);  pd += __shfl_xor(pd, 1, 64);
            ps += __shfl_xor(ps, 2, 64);  pd += __shfl_xor(pd, 2, 64);
            ps += __shfl_xor(ps, 4, 64);  pd += __shfl_xor(pd, 4, 64);
            if (ok && (colg & 7) == 0) {
                als1[(size_t)r * 8 + 2 * nt + b] = ps;
                ald1[(size_t)r * 8 + 2 * nt + b] = pd;
            }
        }
    }
}

// ---------------------------------------------------------------------------
// STREAMING agg1 + fused gemm2/al2: one block per 256-dst partition.
// Edges consumed directly from the partition FIFO (coalesced, no buckets);
// per-dst accumulators in LDS (f32 ds_add atomics, 64 distinct banks ->
// conflict-free). Work proportional to real edges (~17/node), not CAP slots.
// LDS: accs 64KB + dens 8KB + Wsm 4.25KB = 76.25KB -> 2 blocks/CU.
// ---------------------------------------------------------------------------
__global__ __launch_bounds__(512, 2) void sagg1_kernel(
    const bf16_t* __restrict__ hp1,
    const float* __restrict__ als, const float* __restrict__ ald,
    const int* __restrict__ pcnt, const int2* __restrict__ pfifo,
    const float* __restrict__ b1,
    const float* __restrict__ W2,
    const float* __restrict__ a2s, const float* __restrict__ a2d,
    bf16_t* __restrict__ HP2b, float* __restrict__ als2, float* __restrict__ ald2,
    int n)
{
    __shared__ float accs[256][64];
    __shared__ float dens[256][8];
    __shared__ float Wsm[64 * 17];

    const int p = blockIdx.x;
    const int dbase = p << PSHIFT;
    const int nd = min(1 << PSHIFT, n - dbase);
    const int t = threadIdx.x;
    const int wv = t >> 6, lane = t & 63, h = lane >> 3;

    for (int i = t; i < 256 * 64; i += 512) ((float*)accs)[i] = 0.f;
    for (int i = t; i < 256 * 8;  i += 512) ((float*)dens)[i] = 0.f;
    for (int i = t; i < 1024; i += 512) Wsm[(i >> 4) * 17 + (i & 15)] = W2[i];
    __syncthreads();

    int len = pcnt[p]; if (len > CAPP) len = CAPP;
    const int2* f = pfifo + (size_t)p * CAPP;
    const float* aldp = ald + (size_t)dbase * 8;   // 8KB slab, L1-resident

    for (int base = wv * 64; base < len; base += 512) {
        int j = base + lane;
        int2 e = (j < len) ? f[j] : make_int2(0, dbase - 1);
        int mysrc = e.x;
        int mydst = e.y - dbase;                  // -1 sentinel when padded
#pragma unroll 2
        for (int g = 0; g < 64; g += 8) {
            float vv[8], ww[8];
            int dl[8];
#pragma unroll
            for (int u = 0; u < 8; ++u) {
                int src = __shfl(mysrc, g + u, 64);
                int d   = __shfl(mydst, g + u, 64);
                bool ok = d >= 0;
                d = ok ? d : 0;
                dl[u] = d;
                vv[u] = (float)hp1[(size_t)src * D1 + lane];
                float e2 = als[src * 8 + h] + aldp[d * 8 + h];
                e2 = (e2 > 0.f) ? e2 : SLOPE * e2;
                ww[u] = ok ? __expf(e2) : 0.f;
            }
#pragma unroll
            for (int u = 0; u < 8; ++u) {
                atomicAdd(&accs[dl[u]][lane], ww[u] * vv[u]);
                if ((lane & 7) == 0) atomicAdd(&dens[dl[u]][h], ww[u]);
            }
        }
    }
    __syncthreads();

    // epilogue: wave wv handles dsts wv, wv+8, ...
    for (int d = wv; d < nd; d += 8) {
        const int node = dbase + d;
        float v = accs[d][lane] / dens[d][h] + b1[lane];
        v = (v > 0.f) ? v : (__expf(v) - 1.f);    // ELU

        const int g2 = lane >> 4, c = lane & 15;
        float o = 0.f;
#pragma unroll
        for (int kk = 0; kk < 16; ++kk) {
            float hk = __shfl(v, g2 * 16 + kk, 64);
            o = fmaf(hk, Wsm[(g2 * 16 + kk) * 17 + c], o);
        }
        o += __shfl_xor(o, 16, 64);
        o += __shfl_xor(o, 32, 64);
        if (g2 == 0) HP2b[(size_t)node * 16 + c] = (bf16_t)o;

        float rs = o * a2s[c];
        float rd = o * a2d[c];
        rs += __shfl_xor(rs, 1, 64);  rd += __shfl_xor(rd, 1, 64);
        rs += __shfl_xor(rs, 2, 64);  rd += __shfl_xor(rd, 2, 64);
        rs += __shfl_xor(rs, 4, 64);  rd += __shfl_xor(rd, 4, 64);
        rs += __shfl_xor(rs, 8, 64);  rd += __shfl_xor(rd, 8, 64);
        if (lane == 0) { als2[node] = rs; ald2[node] = rd; }
    }
}

// ---------------------------------------------------------------------------
// STREAMING agg2 + log_softmax: one block per partition; 4 edges/wave-iter
// (lane = u*16 + c); LDS acc2[256][16] + den2[256].
// ---------------------------------------------------------------------------
__global__ __launch_bounds__(512, 2) void sagg2_kernel(
    const bf16_t* __restrict__ hp2,
    const float* __restrict__ als, const float* __restrict__ ald,
    const int* __restrict__ pcnt, const int2* __restrict__ pfifo,
    const float* __restrict__ b2,
    float* __restrict__ out, int n)
{
    __shared__ float acc2[256][16];
    __shared__ float den2[256];
    __shared__ float aldS[256];

    const int p = blockIdx.x;
    const int dbase = p << PSHIFT;
    const int nd = min(1 << PSHIFT, n - dbase);
    const int t = threadIdx.x;
    const int wv = t >> 6, lane = t & 63;
    const int u = lane >> 4, c = lane & 15;

    for (int i = t; i < 256 * 16; i += 512) ((float*)acc2)[i] = 0.f;
    for (int i = t; i < 256; i += 512) den2[i] = 0.f;
    for (int i = t; i < nd; i += 512) aldS[i] = ald[dbase + i];
    __syncthreads();

    int len = pcnt[p]; if (len > CAPP) len = CAPP;
    const int2* f = pfifo + (size_t)p * CAPP;

    for (int base = wv * 64; base < len; base += 512) {
        int j = base + lane;
        int2 e = (j < len) ? f[j] : make_int2(0, dbase - 1);
        int mysrc = e.x;
        int mydst = e.y - dbase;
#pragma unroll 4
        for (int g = 0; g < 64; g += 4) {
            int idx = g + u;
            int src = __shfl(mysrc, idx, 64);
            int d   = __shfl(mydst, idx, 64);
            bool ok = d >= 0;
            d = ok ? d : 0;
            float v = (float)hp2[(size_t)src * 16 + c];
            float e2 = als[src] + aldS[d];
            e2 = (e2 > 0.f) ? e2 : SLOPE * e2;
            float w = ok ? __expf(e2) : 0.f;
            atomicAdd(&acc2[d][c], w * v);
            if (c == 0) atomicAdd(&den2[d], w);
        }
    }
    __syncthreads();

    // epilogue: 32 16-lane groups
    const int grp = t >> 4;
    const int c2 = t & 15;
    for (int d = grp; d < nd; d += 32) {
        float v = acc2[d][c2] / den2[d] + b2[c2];
        float mx = v;
        mx = fmaxf(mx, __shfl_xor(mx, 8, 16));
        mx = fmaxf(mx, __shfl_xor(mx, 4, 16));
        mx = fmaxf(mx, __shfl_xor(mx, 2, 16));
        mx = fmaxf(mx, __shfl_xor(mx, 1, 16));
        float ex = __expf(v - mx);
        float sum = ex;
        sum += __shfl_xor(sum, 8, 16);
        sum += __shfl_xor(sum, 4, 16);
        sum += __shfl_xor(sum, 2, 16);
        sum += __shfl_xor(sum, 1, 16);
        out[(size_t)(dbase + d) * 16 + c2] = v - mx - __logf(sum);
    }
}

// ---------------------------------------------------------------------------
extern "C" void kernel_launch(void* const* d_in, const int* in_sizes, int n_in,
                              void* d_out, int out_size, void* d_ws, size_t ws_size,
                              hipStream_t stream)
{
    const float* x      = (const float*)d_in[0];
    const int*   ei     = (const int*)  d_in[1];
    const float* W1     = (const float*)d_in[2];
    const float* a1_src = (const float*)d_in[3];
    const float* a1_dst = (const float*)d_in[4];
    const float* b1     = (const float*)d_in[5];
    const float* W2     = (const float*)d_in[6];
    const float* a2_src = (const float*)d_in[7];
    const float* a2_dst = (const float*)d_in[8];
    const float* b2     = (const float*)d_in[9];
    float* out = (float*)d_out;

    const int N = in_sizes[0] / F_IN;       // 100000
    const int E = in_sizes[1] / 2;          // 1600000
    const int TOT = E + N;                  // edges incl self-loops

    char* base = (char*)d_ws;
    size_t off = 0;
    auto carve = [&](size_t bytes) -> char* {
        char* p = base + off;
        off += (bytes + 255) & ~(size_t)255;
        return p;
    };
    bf16_t* hp1b    = (bf16_t*)carve((size_t)N * D1 * 2);
    int2*   pfifo   = (int2*)  carve((size_t)PPART * CAPP * 8);
    bf16_t* hp2b    = (bf16_t*)carve((size_t)N * 16 * 2);
    float*  als1    = (float*) carve((size_t)N * 8 * 4);
    float*  ald1    = (float*) carve((size_t)N * 8 * 4);
    float*  als2    = (float*) carve((size_t)N * 4);
    float*  ald2    = (float*) carve((size_t)N * 4);
    int*    pcnt    = (int*)   carve((size_t)PPART * 4);
    bf16_t* W1b     = (bf16_t*)carve((size_t)64 * 512 * 2);

    const int Gp = (TOT + CHUNK - 1) / CHUNK;   // part-role blocks
    const int Gg = (N + 127) / 128;             // gemm1-role blocks

    hipMemsetAsync(pcnt, 0, (size_t)PPART * 4, stream);

    wcvt_kernel<<<128, 256, 0, stream>>>(W1, W1b);

    pg_kernel<<<Gg + Gp, 512, 0, stream>>>(ei, pcnt, pfifo,
                                           x, W1b, a1_src, a1_dst,
                                           hp1b, als1, ald1,
                                           E, TOT, Gg, N);

    sagg1_kernel<<<PPART, 512, 0, stream>>>(hp1b, als1, ald1, pcnt, pfifo,
                                            b1, W2, a2_src, a2_dst,
                                            hp2b, als2, ald2, N);

    sagg2_kernel<<<PPART, 512, 0, stream>>>(hp2b, als2, ald2, pcnt, pfifo,
                                            b2, out, N);
}

// Round 9
// 473.428 us; speedup vs baseline: 3.1666x; 3.1666x over previous
//
#include <hip/hip_runtime.h>
#include <hip/hip_bf16.h>

#define N_NODES 100000
#define F_IN    512
#define H1      8
#define C1      8
#define D1      64   // H1*C1
#define C2      16
#define SLOPE   0.2f
#define CAP     48    // bucket capacity per dst; deg ~ Poisson(16)+1
#define PSHIFT  8     // 256 dsts per partition
#define PPART   391   // ceil(100000/256)
#define CAPP    5120  // per-partition FIFO capacity (avg 4352, +11 sigma)
#define CHUNK   2048  // edges per part-role block

typedef __bf16 bf16_t;
typedef bf16_t bf16x8 __attribute__((ext_vector_type(8)));
typedef float  f32x4  __attribute__((ext_vector_type(4)));

// ---------------------------------------------------------------------------
// W1 [512][64] fp32 -> W1^T [64][512] bf16
// ---------------------------------------------------------------------------
__global__ __launch_bounds__(256) void wcvt_kernel(
    const float* __restrict__ W, bf16_t* __restrict__ Bt)
{
    int i = blockIdx.x * 256 + threadIdx.x;     // over 64*512
    if (i >= 64 * 512) return;
    int nn = i >> 9, k = i & 511;
    Bt[i] = (bf16_t)W[k * 64 + nn];
}

// ---------------------------------------------------------------------------
// MERGED gemm1 || part (independent data; part hides under gemm1).
//   blockIdx <  Gg : gemm1 body (bf16 MFMA + fused al1), 128 rows/block
//   blockIdx >= Gg : part body (partition edges into 391 dst-range FIFOs)
// ---------------------------------------------------------------------------
union PgSmem {
    struct {
        int hist[PPART], lofs[PPART], gbase[PPART], cursor[PPART];
        int sdata[512];
        int2 fifo[CHUNK];
    } part;
    bf16_t Bsm[8 * 4 * 64 * 8];
};

__global__ __launch_bounds__(512, 4) void pg_kernel(
    const int* __restrict__ ei, int* __restrict__ pcnt, int2* __restrict__ pfifo,
    const float* __restrict__ X, const bf16_t* __restrict__ Bt,
    const float* __restrict__ a1s, const float* __restrict__ a1d,
    bf16_t* __restrict__ HPb, float* __restrict__ als1, float* __restrict__ ald1,
    int E, int total, int Gg, int n)
{
    __shared__ PgSmem sm;
    const int t = threadIdx.x;

    if ((int)blockIdx.x >= Gg) {
        // ---------------- part body ----------------
        const int chunk0 = ((int)blockIdx.x - Gg) * CHUNK;

        for (int i = t; i < PPART; i += 512) sm.part.hist[i] = 0;
        __syncthreads();

        int srcs[4], dsts[4];
        const int e0 = chunk0 + t * 4;
        if (e0 + 4 <= E) {
            int4 s = *(const int4*)(ei + e0);
            int4 d = *(const int4*)(ei + E + e0);
            srcs[0]=s.x; srcs[1]=s.y; srcs[2]=s.z; srcs[3]=s.w;
            dsts[0]=d.x; dsts[1]=d.y; dsts[2]=d.z; dsts[3]=d.w;
        } else {
#pragma unroll
            for (int j = 0; j < 4; ++j) {
                int e = e0 + j;
                if (e < E)          { srcs[j] = ei[e]; dsts[j] = ei[E + e]; }
                else if (e < total) { srcs[j] = dsts[j] = e - E; }
                else                { srcs[j] = -1;    dsts[j] = -1; }
            }
        }
#pragma unroll
        for (int j = 0; j < 4; ++j)
            if (dsts[j] >= 0) atomicAdd(&sm.part.hist[dsts[j] >> PSHIFT], 1);
        __syncthreads();

        int hv = (t < PPART) ? sm.part.hist[t] : 0;
        sm.part.sdata[t] = hv;
        __syncthreads();
        for (int off = 1; off < 512; off <<= 1) {
            int x = (t >= off) ? sm.part.sdata[t - off] : 0;
            __syncthreads();
            sm.part.sdata[t] += x;
            __syncthreads();
        }
        if (t < PPART) {
            int lo = sm.part.sdata[t] - hv;
            sm.part.lofs[t]   = lo;
            sm.part.cursor[t] = lo;
            sm.part.gbase[t]  = hv ? atomicAdd(&pcnt[t], hv) : 0;
        }
        __syncthreads();

#pragma unroll
        for (int j = 0; j < 4; ++j) {
            if (dsts[j] >= 0) {
                int p = dsts[j] >> PSHIFT;
                int slot = atomicAdd(&sm.part.cursor[p], 1);
                sm.part.fifo[slot] = make_int2(srcs[j], dsts[j]);
            }
        }
        __syncthreads();

        const int w = t >> 6, lane = t & 63;
        for (int p = w; p < PPART; p += 8) {
            int len = sm.part.hist[p];
            int lo  = sm.part.lofs[p];
            int gb  = sm.part.gbase[p];
            int2* dstp = pfifo + (size_t)p * CAPP;
            for (int j = lane; j < len; j += 64) {
                int g = gb + j;
                if (g < CAPP) dstp[g] = sm.part.fifo[lo + j];
            }
        }
        return;
    }

    // ---------------- gemm1 body ----------------
    const int rowbase = (int)blockIdx.x * 128;
    const int w = t >> 6;          // wave 0..7 -> rows w*16..w*16+15
    const int lane = t & 63;

    const int rloc = lane & 15;    // A/B row within 16-group
    const int koff = (lane >> 4) * 8;

    int grow = rowbase + w * 16 + rloc;
    int growc = (grow < n) ? grow : (n - 1);   // clamp for safe loads; store guarded
    const float* arow = X + (size_t)growc * F_IN + koff;

    f32x4 acc[4];
#pragma unroll
    for (int nt = 0; nt < 4; ++nt) acc[nt] = (f32x4){0.f, 0.f, 0.f, 0.f};

#pragma unroll
    for (int half = 0; half < 2; ++half) {
        // stage B fragments for K = half*256 .. half*256+255
        for (int i = t; i < 2048; i += 512) {
            int l9 = i & 63;
            int nt = (i >> 6) & 3;
            int ks = i >> 8;                       // 0..7
            int row = nt * 16 + (l9 & 15);
            int col = (half * 8 + ks) * 32 + (l9 >> 4) * 8;
            *(bf16x8*)(sm.Bsm + (size_t)i * 8) =
                *(const bf16x8*)(Bt + (size_t)row * F_IN + col);
        }
        __syncthreads();

#pragma unroll 4
        for (int ks = 0; ks < 8; ++ks) {
            int kg = (half * 8 + ks) * 32;
            float4 xa0 = *(const float4*)(arow + kg);
            float4 xa1 = *(const float4*)(arow + kg + 4);
            bf16x8 af;
            af[0]=(bf16_t)xa0.x; af[1]=(bf16_t)xa0.y; af[2]=(bf16_t)xa0.z; af[3]=(bf16_t)xa0.w;
            af[4]=(bf16_t)xa1.x; af[5]=(bf16_t)xa1.y; af[6]=(bf16_t)xa1.z; af[7]=(bf16_t)xa1.w;
#pragma unroll
            for (int nt = 0; nt < 4; ++nt) {
                bf16x8 b = *(const bf16x8*)(sm.Bsm + ((ks * 4 + nt) * 64 + lane) * 8);
                acc[nt] = __builtin_amdgcn_mfma_f32_16x16x32_bf16(af, b, acc[nt], 0, 0, 0);
            }
        }
        __syncthreads();
    }

    const int colg = lane & 15;
    const int quad = lane >> 4;
    const int b    = colg >> 3;
    float cs[4], cd[4];
#pragma unroll
    for (int nt = 0; nt < 4; ++nt) {
        cs[nt] = a1s[nt * 16 + colg];
        cd[nt] = a1d[nt * 16 + colg];
    }

#pragma unroll
    for (int i = 0; i < 4; ++i) {
        int r = rowbase + w * 16 + quad * 4 + i;
        bool ok = r < n;
        if (ok) {
            bf16_t* hr = HPb + (size_t)r * D1;
            hr[colg]      = (bf16_t)acc[0][i];
            hr[16 + colg] = (bf16_t)acc[1][i];
            hr[32 + colg] = (bf16_t)acc[2][i];
            hr[48 + colg] = (bf16_t)acc[3][i];
        }
#pragma unroll
        for (int nt = 0; nt < 4; ++nt) {
            float ps = acc[nt][i] * cs[nt];
            float pd = acc[nt][i] * cd[nt];
            ps += __shfl_xor(ps, 1, 64);  pd += __shfl_xor(pd, 1, 64);
            ps += __shfl_xor(ps, 2, 64);  pd += __shfl_xor(pd, 2, 64);
            ps += __shfl_xor(ps, 4, 64);  pd += __shfl_xor(pd, 4, 64);
            if (ok && (colg & 7) == 0) {
                als1[(size_t)r * 8 + 2 * nt + b] = ps;
                ald1[(size_t)r * 8 + 2 * nt + b] = pd;
            }
        }
    }
}

// ---------------------------------------------------------------------------
// pagg1: one block per 256-dst partition. IN-LDS PLACE preamble (reads the
// partition FIFO once, scatters into lbuck[256][48] via LDS atomics), then
// R7's proven per-node wave-parallel phase-A/phase-B + fused gemm2/al2.
// Deletes the place dispatch + 38MB of global bucket traffic.
// LDS: lbuck 48K + lcnt 1K + Wsm 4.25K + wbuf 12.5K = ~67K -> 2 blocks/CU,
// all 391 blocks resident (no tail).
// ---------------------------------------------------------------------------
#define P1SEC(G0)                                                           \
    {                                                                       \
        _Pragma("unroll")                                                   \
        for (int j = G0; j < G0 + 8; ++j) {                                 \
            int s = lbuck[d][j];                                            \
            s = (j < m) ? s : 0;                                            \
            float wgt = wbuf[wv][h][j];                                     \
            float v = (float)hp1[(size_t)s * D1 + lane];                    \
            acc = fmaf(wgt, v, acc);                                        \
        }                                                                   \
    }

__global__ __launch_bounds__(512, 2) void pagg1_kernel(
    const bf16_t* __restrict__ hp1,
    const float* __restrict__ als, const float* __restrict__ ald,
    const int* __restrict__ pcnt, const int2* __restrict__ pfifo,
    const float* __restrict__ b1,
    const float* __restrict__ W2,
    const float* __restrict__ a2s, const float* __restrict__ a2d,
    bf16_t* __restrict__ HP2b, float* __restrict__ als2, float* __restrict__ ald2,
    int n)
{
    __shared__ int   lcnt[256];
    __shared__ int   lbuck[256][CAP];
    __shared__ float Wsm[64 * 17];
    __shared__ float wbuf[8][8][50];

    const int p = blockIdx.x;
    const int dbase = p << PSHIFT;
    const int nd = min(1 << PSHIFT, n - dbase);
    const int t = threadIdx.x;
    const int wv = t >> 6, lane = t & 63, h = lane >> 3;

    for (int i = t; i < 256; i += 512) lcnt[i] = 0;
    for (int i = t; i < 1024; i += 512) Wsm[(i >> 4) * 17 + (i & 15)] = W2[i];
    __syncthreads();

    // ---- in-LDS place ----
    int len = pcnt[p]; if (len > CAPP) len = CAPP;
    const int2* f = pfifo + (size_t)p * CAPP;
    for (int i = t; i < len; i += 512) {
        int2 e = f[i];
        int d = e.y - dbase;
        int s = atomicAdd(&lcnt[d], 1);
        if (s < CAP) lbuck[d][s] = e.x;
    }
    __syncthreads();

    // ---- per-node wave-parallel aggregation (R7 structure) ----
    for (int d = wv; d < nd; d += 8) {
        const int node = dbase + d;
        int m = lcnt[d]; if (m > CAP) m = CAP;
        float ad = ald[node * 8 + h];

        // phase A: 6 weights per lane
        const int jbase = lane & 7;
        float wsum = 0.f;
#pragma unroll
        for (int r = 0; r < 6; ++r) {
            int j = jbase + 8 * r;
            int s = (j < m) ? lbuck[d][j] : 0;
            float e = als[s * 8 + h] + ad;
            e = (e > 0.f) ? e : SLOPE * e;
            float wgt = (j < m) ? __expf(e) : 0.f;
            wbuf[wv][h][j] = wgt;
            wsum += wgt;
        }
        wsum += __shfl_xor(wsum, 1, 64);
        wsum += __shfl_xor(wsum, 2, 64);
        wsum += __shfl_xor(wsum, 4, 64);
        const float den = wsum;

        // phase B: LDS-bucket gathers (wave-uniform index, high MLP)
        float acc = 0.f;
        P1SEC(0);
        if (m > 8)  P1SEC(8);
        if (m > 16) P1SEC(16);
        if (m > 24) P1SEC(24);
        if (m > 32) P1SEC(32);
        if (m > 40) P1SEC(40);

        float v = acc / den + b1[lane];
        v = (v > 0.f) ? v : (__expf(v) - 1.f);    // ELU — h1[node][lane]

        // fused gemm2: hp2[c] = sum_k h[k] * W2[k][c]
        const int g2 = lane >> 4, c = lane & 15;
        float o = 0.f;
#pragma unroll
        for (int kk = 0; kk < 16; ++kk) {
            float hk = __shfl(v, g2 * 16 + kk, 64);
            o = fmaf(hk, Wsm[(g2 * 16 + kk) * 17 + c], o);
        }
        o += __shfl_xor(o, 16, 64);
        o += __shfl_xor(o, 32, 64);      // all lanes hold hp2[c]
        if (g2 == 0) HP2b[(size_t)node * 16 + c] = (bf16_t)o;

        float rs = o * a2s[c];
        float rd = o * a2d[c];
        rs += __shfl_xor(rs, 1, 64);  rd += __shfl_xor(rd, 1, 64);
        rs += __shfl_xor(rs, 2, 64);  rd += __shfl_xor(rd, 2, 64);
        rs += __shfl_xor(rs, 4, 64);  rd += __shfl_xor(rd, 4, 64);
        rs += __shfl_xor(rs, 8, 64);  rd += __shfl_xor(rd, 8, 64);
        if (lane == 0) { als2[node] = rs; ald2[node] = rd; }
    }
}

// ---------------------------------------------------------------------------
// pagg2: same in-LDS place preamble, then 16-lane-group per node (R7's agg2
// structure) + log_softmax.
// LDS: lbuck 48K + lcnt 1K + wbuf2 6.25K + aldS 1K = ~56K -> 2 blocks/CU.
// ---------------------------------------------------------------------------
#define P2SEC(G0)                                                           \
    {                                                                       \
        _Pragma("unroll")                                                   \
        for (int j = G0; j < G0 + 8; ++j) {                                 \
            int s = lbuck[d][j];                                            \
            s = (j < m) ? s : 0;                                            \
            float wgt = wbuf2[grp][j];                                      \
            float v = (float)hp2[(size_t)s * 16 + c];                       \
            acc = fmaf(wgt, v, acc);                                        \
        }                                                                   \
    }

__global__ __launch_bounds__(512, 2) void pagg2_kernel(
    const bf16_t* __restrict__ hp2,
    const float* __restrict__ als, const float* __restrict__ ald,
    const int* __restrict__ pcnt, const int2* __restrict__ pfifo,
    const float* __restrict__ b2,
    float* __restrict__ out, int n)
{
    __shared__ int   lcnt[256];
    __shared__ int   lbuck[256][CAP];
    __shared__ float wbuf2[32][50];
    __shared__ float aldS[256];

    const int p = blockIdx.x;
    const int dbase = p << PSHIFT;
    const int nd = min(1 << PSHIFT, n - dbase);
    const int t = threadIdx.x;
    const int grp = t >> 4, c = t & 15;       // 32 groups of 16 lanes

    for (int i = t; i < 256; i += 512) lcnt[i] = 0;
    for (int i = t; i < nd; i += 512) aldS[i] = ald[dbase + i];
    __syncthreads();

    // ---- in-LDS place ----
    int len = pcnt[p]; if (len > CAPP) len = CAPP;
    const int2* f = pfifo + (size_t)p * CAPP;
    for (int i = t; i < len; i += 512) {
        int2 e = f[i];
        int d = e.y - dbase;
        int s = atomicAdd(&lcnt[d], 1);
        if (s < CAP) lbuck[d][s] = e.x;
    }
    __syncthreads();

    // ---- per-node 16-lane aggregation ----
    for (int d = grp; d < nd; d += 32) {
        const int node = dbase + d;
        int m = lcnt[d]; if (m > CAP) m = CAP;
        float ad = aldS[d];

        // phase A: 3 weights per lane
        float wsum = 0.f;
#pragma unroll
        for (int r = 0; r < 3; ++r) {
            int j = c + 16 * r;
            int s = (j < m) ? lbuck[d][j] : 0;
            float e = als[s] + ad;
            e = (e > 0.f) ? e : SLOPE * e;
            float wgt = (j < m) ? __expf(e) : 0.f;
            wbuf2[grp][j] = wgt;
            wsum += wgt;
        }
        wsum += __shfl_xor(wsum, 1, 16);
        wsum += __shfl_xor(wsum, 2, 16);
        wsum += __shfl_xor(wsum, 4, 16);
        wsum += __shfl_xor(wsum, 8, 16);
        const float den = wsum;

        // phase B
        float acc = 0.f;
        P2SEC(0);
        if (m > 8)  P2SEC(8);
        if (m > 16) P2SEC(16);
        if (m > 24) P2SEC(24);
        if (m > 32) P2SEC(32);
        if (m > 40) P2SEC(40);

        float v = acc / den + b2[c];

        float mx = v;
        mx = fmaxf(mx, __shfl_xor(mx, 8, 16));
        mx = fmaxf(mx, __shfl_xor(mx, 4, 16));
        mx = fmaxf(mx, __shfl_xor(mx, 2, 16));
        mx = fmaxf(mx, __shfl_xor(mx, 1, 16));
        float ex = __expf(v - mx);
        float sum = ex;
        sum += __shfl_xor(sum, 8, 16);
        sum += __shfl_xor(sum, 4, 16);
        sum += __shfl_xor(sum, 2, 16);
        sum += __shfl_xor(sum, 1, 16);
        out[(size_t)node * 16 + c] = v - mx - __logf(sum);
    }
}

// ---------------------------------------------------------------------------
extern "C" void kernel_launch(void* const* d_in, const int* in_sizes, int n_in,
                              void* d_out, int out_size, void* d_ws, size_t ws_size,
                              hipStream_t stream)
{
    const float* x      = (const float*)d_in[0];
    const int*   ei     = (const int*)  d_in[1];
    const float* W1     = (const float*)d_in[2];
    const float* a1_src = (const float*)d_in[3];
    const float* a1_dst = (const float*)d_in[4];
    const float* b1     = (const float*)d_in[5];
    const float* W2     = (const float*)d_in[6];
    const float* a2_src = (const float*)d_in[7];
    const float* a2_dst = (const float*)d_in[8];
    const float* b2     = (const float*)d_in[9];
    float* out = (float*)d_out;

    const int N = in_sizes[0] / F_IN;       // 100000
    const int E = in_sizes[1] / 2;          // 1600000
    const int TOT = E + N;                  // edges incl self-loops

    char* base = (char*)d_ws;
    size_t off = 0;
    auto carve = [&](size_t bytes) -> char* {
        char* p = base + off;
        off += (bytes + 255) & ~(size_t)255;
        return p;
    };
    bf16_t* hp1b    = (bf16_t*)carve((size_t)N * D1 * 2);
    int2*   pfifo   = (int2*)  carve((size_t)PPART * CAPP * 8);
    bf16_t* hp2b    = (bf16_t*)carve((size_t)N * 16 * 2);
    float*  als1    = (float*) carve((size_t)N * 8 * 4);
    float*  ald1    = (float*) carve((size_t)N * 8 * 4);
    float*  als2    = (float*) carve((size_t)N * 4);
    float*  ald2    = (float*) carve((size_t)N * 4);
    int*    pcnt    = (int*)   carve((size_t)PPART * 4);
    bf16_t* W1b     = (bf16_t*)carve((size_t)64 * 512 * 2);

    const int Gp = (TOT + CHUNK - 1) / CHUNK;   // part-role blocks
    const int Gg = (N + 127) / 128;             // gemm1-role blocks

    hipMemsetAsync(pcnt, 0, (size_t)PPART * 4, stream);

    wcvt_kernel<<<128, 256, 0, stream>>>(W1, W1b);

    pg_kernel<<<Gg + Gp, 512, 0, stream>>>(ei, pcnt, pfifo,
                                           x, W1b, a1_src, a1_dst,
                                           hp1b, als1, ald1,
                                           E, TOT, Gg, N);

    pagg1_kernel<<<PPART, 512, 0, stream>>>(hp1b, als1, ald1, pcnt, pfifo,
                                            b1, W2, a2_src, a2_dst,
                                            hp2b, als2, ald2, N);

    pagg2_kernel<<<PPART, 512, 0, stream>>>(hp2b, als2, ald2, pcnt, pfifo,
                                            b2, out, N);
}